// Round 15
// baseline (137.834 us; speedup 1.0000x reference)
//
#include <hip/hip_runtime.h>
#include <stdint.h>
#include <stddef.h>

typedef _Float16 half_t;
typedef __attribute__((ext_vector_type(2))) __fp16 fp16v2;
typedef __attribute__((ext_vector_type(4))) _Float16 f16x4;
typedef __attribute__((ext_vector_type(8))) _Float16 f16x8;
typedef __attribute__((ext_vector_type(4))) float f32x4;

#define EPSF 1.1920928955078125e-07f
#define LOG2E 1.4426950408889634f

#define AS1 __attribute__((address_space(1)))
#define AS3 __attribute__((address_space(3)))

// workspace layout (offsets in half elements)
#define WS_XN   0u          // [8192][512]   normalized tokens, fp16
#define WS_WQT  4194304u    // [1536][512]   w_qkv^T fp16
#define WS_WOT  4980736u    // [512][512]    w_out^T fp16
#define WS_Q    5242880u    // [16][4096][64]  (pre-scaled by log2e)
#define WS_K    9437184u    // [16][4096][64]
#define WS_VT   13631488u   // [16][64][4096]  V^T, kv-cols PERMUTED in 32-chunks
#define WS_AO   17825792u   // [8192][512]   attention output fp16
#define WS_NEED_BYTES 44040192u

__device__ __forceinline__ void gload16(const void* g, void* l) {
  __builtin_amdgcn_global_load_lds((const AS1 void*)g, (AS3 void*)l, 16, 0, 0);
}

__device__ __forceinline__ float fast_exp2(float x) {
#if __has_builtin(__builtin_amdgcn_exp2f)
  return __builtin_amdgcn_exp2f(x);
#else
  return exp2f(x);
#endif
}

// ---------------- RMSNorm + fp16 cast ----------------
__global__ __launch_bounds__(256) void k_rmsnorm(const float* __restrict__ t,
                                                 const float* __restrict__ w,
                                                 half_t* __restrict__ xn) {
  int row = blockIdx.x * 4 + (threadIdx.x >> 6);
  int ln = threadIdx.x & 63;
  const float* src = t + (size_t)row * 512 + ln * 8;
  float4 a = *(const float4*)src;
  float4 b = *(const float4*)(src + 4);
  float ss = a.x * a.x + a.y * a.y + a.z * a.z + a.w * a.w
           + b.x * b.x + b.y * b.y + b.z * b.z + b.w * b.w;
#pragma unroll
  for (int m = 32; m >= 1; m >>= 1) ss += __shfl_xor(ss, m);
  float r = rsqrtf(ss * (1.0f / 512.0f) + EPSF);
  const float* wp = w + ln * 8;
  float4 w0 = *(const float4*)wp;
  float4 w1 = *(const float4*)(wp + 4);
  f16x8 o;
  o[0] = (_Float16)(a.x * r * w0.x);
  o[1] = (_Float16)(a.y * r * w0.y);
  o[2] = (_Float16)(a.z * r * w0.z);
  o[3] = (_Float16)(a.w * r * w0.w);
  o[4] = (_Float16)(b.x * r * w1.x);
  o[5] = (_Float16)(b.y * r * w1.y);
  o[6] = (_Float16)(b.z * r * w1.z);
  o[7] = (_Float16)(b.w * r * w1.w);
  *(f16x8*)(xn + (size_t)row * 512 + ln * 8) = o;
}

// ---------------- fused coalesced weight transpose+cast (wqkv & wout) ----------------
__global__ __launch_bounds__(256) void k_wtrans(const float* __restrict__ wqkv,
                                                const float* __restrict__ wout,
                                                half_t* __restrict__ wqt,
                                                half_t* __restrict__ wot) {
  __shared__ half_t tile[64][65];
  int b = blockIdx.x;
  const float* src; half_t* dst; int N, tk, tn;
  if (b < 192) { src = wqkv; dst = wqt; N = 1536; tk = b / 24; tn = b - tk * 24; }
  else { b -= 192; src = wout; dst = wot; N = 512; tk = b >> 3; tn = b & 7; }
  int c = threadIdx.x & 63;
  int r0 = threadIdx.x >> 6;
#pragma unroll
  for (int i = 0; i < 16; ++i) {
    int r = i * 4 + r0;
    tile[r][c] = (_Float16)src[(size_t)(tk * 64 + r) * N + tn * 64 + c];
  }
  __syncthreads();
#pragma unroll
  for (int i = 0; i < 16; ++i) {
    int n = i * 4 + r0;
    dst[(size_t)(tn * 64 + n) * 512 + tk * 64 + c] = tile[c][n];
  }
}

// ---------------- shared GEMM core: C[128][128] tile = A[M][K] @ Bt[N][K]^T ----------------
__device__ __forceinline__ void gemm_core(const half_t* __restrict__ A,
                                          const half_t* __restrict__ Bt,
                                          int m0, int n0, int Ksz,
                                          half_t* Al, half_t* Bl,
                                          f32x4 acc[4][4]) {
  int wv = threadIdx.x >> 6, ln = threadIdx.x & 63;
  int wm = (wv >> 1) << 6, wn = (wv & 1) << 6;
  for (int kt = 0; kt < Ksz; kt += 64) {
#pragma unroll
    for (int i = 0; i < 4; ++i) {
      int seg = wv * 4 + i;          // 16 segs x 8 rows = 128 rows
      int r = seg * 8 + (ln >> 3);
      int cb = ((ln & 7) * 16) ^ ((r & 7) << 4);   // pre-swizzled source col
      gload16((const char*)(A + (size_t)(m0 + r) * Ksz + kt) + cb, (char*)Al + seg * 1024);
      gload16((const char*)(Bt + (size_t)(n0 + r) * Ksz + kt) + cb, (char*)Bl + seg * 1024);
    }
    __syncthreads();
#pragma unroll
    for (int kc = 0; kc < 2; ++kc) {
      f16x8 af[4], bf[4];
#pragma unroll
      for (int mt = 0; mt < 4; ++mt) {
        int rr = wm + mt * 16 + (ln & 15);
        af[mt] = *(const f16x8*)((const char*)Al + rr * 128 +
                                 ((kc * 64 + (ln >> 4) * 16) ^ ((rr & 7) << 4)));
      }
#pragma unroll
      for (int nt = 0; nt < 4; ++nt) {
        int rr = wn + nt * 16 + (ln & 15);
        bf[nt] = *(const f16x8*)((const char*)Bl + rr * 128 +
                                 ((kc * 64 + (ln >> 4) * 16) ^ ((rr & 7) << 4)));
      }
#pragma unroll
      for (int mt = 0; mt < 4; ++mt)
#pragma unroll
        for (int nt = 0; nt < 4; ++nt)
          acc[mt][nt] = __builtin_amdgcn_mfma_f32_16x16x32_f16(af[mt], bf[nt], acc[mt][nt], 0, 0, 0);
    }
    __syncthreads();
  }
}

// ---------------- QKV GEMM: scatter q (log2e-scaled) / k / vT (k-slot-permuted) ----------------
__global__ __launch_bounds__(256, 2) void k_gemm_qkv(const half_t* __restrict__ A,
                                                     const half_t* __restrict__ Bt,
                                                     half_t* __restrict__ q,
                                                     half_t* __restrict__ kk,
                                                     half_t* __restrict__ vt) {
  __shared__ __align__(16) half_t Al[128 * 64];
  __shared__ __align__(16) half_t Bl[128 * 64];
  f32x4 acc[4][4];
  f32x4 z = {0.f, 0.f, 0.f, 0.f};
#pragma unroll
  for (int i = 0; i < 4; ++i)
#pragma unroll
    for (int j = 0; j < 4; ++j) acc[i][j] = z;
  int m0 = blockIdx.x * 128, n0 = blockIdx.y * 128;
  gemm_core(A, Bt, m0, n0, 512, Al, Bl, acc);
  int wv = threadIdx.x >> 6, ln = threadIdx.x & 63;
  int wm = (wv >> 1) << 6, wn = (wv & 1) << 6;
#pragma unroll
  for (int mt = 0; mt < 4; ++mt) {
#pragma unroll
    for (int nt = 0; nt < 4; ++nt) {
      int gn = n0 + wn + nt * 16 + (ln & 15);
      int qkv_i = gn >> 9;         // 0,1,2
      int h = (gn >> 6) & 7;
      int d = gn & 63;
#pragma unroll
      for (int j = 0; j < 4; ++j) {
        int gm = m0 + wm + mt * 16 + (ln >> 4) * 4 + j;   // token id
        int head = ((gm >> 12) << 3) | h;                 // b*8+h
        int n = gm & 4095;
        float av = acc[mt][nt][j];
        if (qkv_i == 0)      q [((size_t)head * 4096 + n) * 64 + d] = (_Float16)(av * LOG2E);
        else if (qkv_i == 1) kk[((size_t)head * 4096 + n) * 64 + d] = (_Float16)av;
        else {
          // V^T with kv-col permutation within each aligned 32-chunk:
          // kv = h16*16 + g*4 + j2  ->  pos = g*8 + h16*4 + j2
          int pcol = (n & ~31) | (((n >> 2) & 3) << 3) | (((n >> 4) & 1) << 2) | (n & 3);
          vt[((size_t)head * 64 + d) * 4096 + pcol] = (_Float16)av;
        }
      }
    }
  }
}

// ---------------- out GEMM: [8192,512]@[512,512] -> fp32 d_out ----------------
__global__ __launch_bounds__(256, 2) void k_gemm_out(const half_t* __restrict__ A,
                                                     const half_t* __restrict__ Bt,
                                                     float* __restrict__ out) {
  __shared__ __align__(16) half_t Al[128 * 64];
  __shared__ __align__(16) half_t Bl[128 * 64];
  f32x4 acc[4][4];
  f32x4 z = {0.f, 0.f, 0.f, 0.f};
#pragma unroll
  for (int i = 0; i < 4; ++i)
#pragma unroll
    for (int j = 0; j < 4; ++j) acc[i][j] = z;
  int m0 = blockIdx.x * 128, n0 = blockIdx.y * 128;
  gemm_core(A, Bt, m0, n0, 512, Al, Bl, acc);
  int wv = threadIdx.x >> 6, ln = threadIdx.x & 63;
  int wm = (wv >> 1) << 6, wn = (wv & 1) << 6;
#pragma unroll
  for (int mt = 0; mt < 4; ++mt)
#pragma unroll
    for (int nt = 0; nt < 4; ++nt) {
      int gn = n0 + wn + nt * 16 + (ln & 15);
#pragma unroll
      for (int j = 0; j < 4; ++j) {
        int gm = m0 + wm + mt * 16 + (ln >> 4) * 4 + j;
        out[(size_t)gm * 512 + gn] = acc[mt][nt][j];
      }
    }
}

// ---------------- flash attention: 4-wave blocks x 16 q rows, QBLK=64, grid 1024 ----------------
// Same per-wave code as R13 (best verified), but 4 independent barrier domains
// per CU (4 blocks x 4 waves = 16 waves/CU, same occupancy): while one block
// drains its __syncthreads, the other blocks' waves keep the SIMDs fed.
// S^T = mfma(K,Q) C-init=-mrun; shfl-free defer-max; O^T = mfma(V^T,P^T);
// l = mfma(ones,P^T).
__global__ __launch_bounds__(256, 4) void k_attn(const half_t* __restrict__ q,
                                                 const half_t* __restrict__ kg,
                                                 const half_t* __restrict__ vt,
                                                 half_t* __restrict__ ao) {
  __shared__ __align__(16) char lds[32768];   // [2 bufs][K 8KB | V^T 8KB]
  const int wv = threadIdx.x >> 6, ln = threadIdx.x & 63;
  const int bid = blockIdx.x;
  const int lin = (bid & 7) * 128 + (bid >> 3);   // XCD-chunk swizzle (1024 = 8*128)
  const int head = lin >> 6;
  const int qt = lin & 63;
  const int q0 = qt * 64 + wv * 16;
  const char* qh = (const char*)(q  + (size_t)head * 4096 * 64);
  const char* kh = (const char*)(kg + (size_t)head * 4096 * 64);
  const char* vh = (const char*)(vt + (size_t)head * 64 * 4096);

  // Q fragments (B-operand: col = q-row = ln&15, k-slots = d)
  f16x8 qf[2];
#pragma unroll
  for (int kc = 0; kc < 2; ++kc) {
    int r = q0 + (ln & 15);
    qf[kc] = *(const f16x8*)(qh + (size_t)r * 128 + kc * 64 + (ln >> 4) * 16);
  }

  // staging: two K segs + two V segs per wave (4 waves cover 8KB each)
  const char* ks[2]; const char* vs[2]; int lo[2];
#pragma unroll
  for (int i = 0; i < 2; ++i) {
    int seg = wv * 2 + i;
    int r = seg * 8 + (ln >> 3);
    int cb = ((ln & 7) * 16) ^ ((r & 7) << 4);
    ks[i] = kh + (size_t)r * 128 + cb;
    vs[i] = vh + (size_t)r * 8192 + cb;
    lo[i] = seg * 1024;
  }

  float mrun = 0.0f;       // relative defer-max: m >= truemax-11 holds from tile 0
  f32x4 oacc[4];
  f32x4 lacc;
  const f32x4 z = {0.f, 0.f, 0.f, 0.f};
  lacc = z;
#pragma unroll
  for (int dt = 0; dt < 4; ++dt) oacc[dt] = z;
  f16x8 ones;
#pragma unroll
  for (int e = 0; e < 8; ++e) ones[e] = (_Float16)1.0f;

  // prologue: stage tile 0 into buf 0
  gload16(ks[0], lds + lo[0]); gload16(ks[1], lds + lo[1]);
  gload16(vs[0], lds + 8192 + lo[0]); gload16(vs[1], lds + 8192 + lo[1]);
  ks[0] += 8192; ks[1] += 8192; vs[0] += 128; vs[1] += 128;
  __syncthreads();

  int cur = 0;
#pragma unroll 1
  for (int t = 0; t < 64; ++t) {
    if (t < 63) {   // issue next-tile prefetch first; lands during compute
      char* base = lds + (cur ^ 1) * 16384;
      gload16(ks[0], base + lo[0]); gload16(ks[1], base + lo[1]);
      gload16(vs[0], base + 8192 + lo[0]); gload16(vs[1], base + 8192 + lo[1]);
      ks[0] += 8192; ks[1] += 8192; vs[0] += 128; vs[1] += 128;
    }
    const char* Kb = lds + cur * 16384;
    const char* Vb = Kb + 8192;

    // S^T = K * Q^T - m : C[row=kv][col=q], C-init = -mrun (per-lane q max)
    f32x4 s[4];
    {
      float nm = -mrun;
      f32x4 mi = {nm, nm, nm, nm};
      s[0] = mi; s[1] = mi; s[2] = mi; s[3] = mi;
    }
    __builtin_amdgcn_s_setprio(1);
#pragma unroll
    for (int kc = 0; kc < 2; ++kc) {
      f16x8 kf[4];
#pragma unroll
      for (int kt = 0; kt < 4; ++kt) {
        int rr = kt * 16 + (ln & 15);
        kf[kt] = *(const f16x8*)(Kb + rr * 128 + ((kc * 64 + (ln >> 4) * 16) ^ ((rr & 7) << 4)));
      }
#pragma unroll
      for (int kt = 0; kt < 4; ++kt)
        s[kt] = __builtin_amdgcn_mfma_f32_16x16x32_f16(kf[kt], qf[kc], s[kt], 0, 0, 0);
    }
    __builtin_amdgcn_s_setprio(0);

    // V fragments: single b128 per (kc,dt) thanks to k-slot-permuted global layout
    f16x8 vf[2][4];
#pragma unroll
    for (int dt = 0; dt < 4; ++dt) {
      int rr = dt * 16 + (ln & 15);
      int sw = (rr & 7) << 4;
      vf[0][dt] = *(const f16x8*)(Vb + rr * 128 + (((ln >> 4) * 16) ^ sw));
      vf[1][dt] = *(const f16x8*)(Vb + rr * 128 + ((64 + (ln >> 4) * 16) ^ sw));
    }

    // online softmax (log2 domain, already max-relative); one q per lane
    f16x8 pf[2];
    {
      // 16-value max in max3-friendly nested-triple shape (8 ops)
      float m0 = fmaxf(fmaxf(s[0][0], s[0][1]), s[0][2]);
      float m1 = fmaxf(fmaxf(s[0][3], s[1][0]), s[1][1]);
      float m2 = fmaxf(fmaxf(s[1][2], s[1][3]), s[2][0]);
      float m3 = fmaxf(fmaxf(s[2][1], s[2][2]), s[2][3]);
      float m4 = fmaxf(fmaxf(s[3][0], s[3][1]), s[3][2]);
      float m5 = fmaxf(fmaxf(m0, m1), m2);
      float m6 = fmaxf(fmaxf(m3, m4), s[3][3]);
      float tm = fmaxf(m5, m6);
      float p[4][4];
      // __any fires if ANY lane's LOCAL max breaches headroom; cross-lane max
      // (ds_bpermute-backed shfls) only needed to compute dlt in the rare path.
      if (__builtin_expect(__any(tm > 11.0f), 0)) {   // rare rescale path
        tm = fmaxf(tm, __shfl_xor(tm, 16));           // per-q max over 4 groups
        tm = fmaxf(tm, __shfl_xor(tm, 32));
        float dlt = fmaxf(tm, 0.0f);
        float sc = fast_exp2(-dlt);
        mrun += dlt;
        lacc[0] *= sc;
#pragma unroll
        for (int dt = 0; dt < 4; ++dt) {
          oacc[dt][0] *= sc; oacc[dt][1] *= sc;
          oacc[dt][2] *= sc; oacc[dt][3] *= sc;
        }
#pragma unroll
        for (int kt = 0; kt < 4; ++kt)
#pragma unroll
          for (int r = 0; r < 4; ++r) p[kt][r] = fast_exp2(s[kt][r] - dlt);
      } else {                                        // common path: shfl-free
#pragma unroll
        for (int kt = 0; kt < 4; ++kt)
#pragma unroll
          for (int r = 0; r < 4; ++r) p[kt][r] = fast_exp2(s[kt][r]);
      }
#pragma unroll
      for (int kc = 0; kc < 2; ++kc) {
        union { f16x8 v; fp16v2 h[4]; } u;
        u.h[0] = __builtin_amdgcn_cvt_pkrtz(p[2 * kc][0], p[2 * kc][1]);
        u.h[1] = __builtin_amdgcn_cvt_pkrtz(p[2 * kc][2], p[2 * kc][3]);
        u.h[2] = __builtin_amdgcn_cvt_pkrtz(p[2 * kc + 1][0], p[2 * kc + 1][1]);
        u.h[3] = __builtin_amdgcn_cvt_pkrtz(p[2 * kc + 1][2], p[2 * kc + 1][3]);
        pf[kc] = u.v;
      }
    }

    // O^T += V^T * P^T ; l += ones * P^T (full kv sum lands in every lane)
    __builtin_amdgcn_s_setprio(1);
#pragma unroll
    for (int dt = 0; dt < 4; ++dt)
      oacc[dt] = __builtin_amdgcn_mfma_f32_16x16x32_f16(vf[0][dt], pf[0], oacc[dt], 0, 0, 0);
    lacc = __builtin_amdgcn_mfma_f32_16x16x32_f16(ones, pf[0], lacc, 0, 0, 0);
#pragma unroll
    for (int dt = 0; dt < 4; ++dt)
      oacc[dt] = __builtin_amdgcn_mfma_f32_16x16x32_f16(vf[1][dt], pf[1], oacc[dt], 0, 0, 0);
    lacc = __builtin_amdgcn_mfma_f32_16x16x32_f16(ones, pf[1], lacc, 0, 0, 0);
    __builtin_amdgcn_s_setprio(0);

    __syncthreads();   // drains vmcnt; prefetch had full compute phase to land
    cur ^= 1;
  }

  // epilogue: O^T / l -> attn_out [token][h*64+d] fp16
  const int b = head >> 3, h = head & 7;
  {
    float inv = 1.0f / lacc[0];
    int n = q0 + (ln & 15);
    half_t* dst = ao + ((size_t)(b * 4096 + n)) * 512 + h * 64 + (ln >> 4) * 4;
#pragma unroll
    for (int dt = 0; dt < 4; ++dt) {
      f16x4 o4;
      o4[0] = (_Float16)(oacc[dt][0] * inv);
      o4[1] = (_Float16)(oacc[dt][1] * inv);
      o4[2] = (_Float16)(oacc[dt][2] * inv);
      o4[3] = (_Float16)(oacc[dt][3] * inv);
      *(f16x4*)(dst + dt * 16) = o4;
    }
  }
}

extern "C" void kernel_launch(void* const* d_in, const int* in_sizes, int n_in,
                              void* d_out, int out_size, void* d_ws, size_t ws_size,
                              hipStream_t stream) {
  if (ws_size < WS_NEED_BYTES) return;  // loud failure if scratch too small
  const float* tokens = (const float*)d_in[0];
  const float* nw     = (const float*)d_in[1];
  const float* wqkv   = (const float*)d_in[2];
  const float* wout   = (const float*)d_in[3];
  float* out = (float*)d_out;
  half_t* ws = (half_t*)d_ws;
  half_t* xn  = ws + WS_XN;
  half_t* wqt = ws + WS_WQT;
  half_t* wot = ws + WS_WOT;
  half_t* qb  = ws + WS_Q;
  half_t* kb  = ws + WS_K;
  half_t* vtb = ws + WS_VT;
  half_t* aob = ws + WS_AO;

  k_rmsnorm<<<2048, 256, 0, stream>>>(tokens, nw, xn);
  k_wtrans<<<256, 256, 0, stream>>>(wqkv, wout, wqt, wot);
  k_gemm_qkv<<<dim3(64, 12), 256, 0, stream>>>(xn, wqt, qb, kb, vtb);
  k_attn<<<1024, 256, 0, stream>>>(qb, kb, vtb, aob);
  k_gemm_out<<<dim3(64, 4), 256, 0, stream>>>(aob, wot, out);
}

// Round 16
// 127.067 us; speedup vs baseline: 1.0847x; 1.0847x over previous
//
#include <hip/hip_runtime.h>
#include <stdint.h>
#include <stddef.h>

typedef _Float16 half_t;
typedef __attribute__((ext_vector_type(2))) __fp16 fp16v2;
typedef __attribute__((ext_vector_type(4))) _Float16 f16x4;
typedef __attribute__((ext_vector_type(8))) _Float16 f16x8;
typedef __attribute__((ext_vector_type(4))) float f32x4;

#define EPSF 1.1920928955078125e-07f
#define LOG2E 1.4426950408889634f

#define AS1 __attribute__((address_space(1)))
#define AS3 __attribute__((address_space(3)))

// workspace layout (offsets in half elements)
#define WS_XN   0u          // [8192][512]   normalized tokens, fp16
#define WS_WQT  4194304u    // [1536][512]   w_qkv^T fp16
#define WS_WOT  4980736u    // [512][512]    w_out^T fp16
#define WS_Q    5242880u    // [16][4096][64]  (pre-scaled by log2e)
#define WS_K    9437184u    // [16][4096][64]
#define WS_VT   13631488u   // [16][64][4096]  V^T, kv-cols PERMUTED in 32-chunks
#define WS_AO   17825792u   // [8192][512]   attention output fp16
#define WS_NEED_BYTES 44040192u

__device__ __forceinline__ void gload16(const void* g, void* l) {
  __builtin_amdgcn_global_load_lds((const AS1 void*)g, (AS3 void*)l, 16, 0, 0);
}

__device__ __forceinline__ float fast_exp2(float x) {
#if __has_builtin(__builtin_amdgcn_exp2f)
  return __builtin_amdgcn_exp2f(x);
#else
  return exp2f(x);
#endif
}

// ---------------- fused prep: RMSNorm+cast (blocks 0..2047) | weight transpose (2048..2303) ----------------
__global__ __launch_bounds__(256) void k_prep(const float* __restrict__ t,
                                              const float* __restrict__ w,
                                              half_t* __restrict__ xn,
                                              const float* __restrict__ wqkv,
                                              const float* __restrict__ wout,
                                              half_t* __restrict__ wqt,
                                              half_t* __restrict__ wot) {
  __shared__ half_t tile[64][65];
  if (blockIdx.x < 2048) {
    // RMSNorm + fp16 cast: 4 rows per block, one wave per row
    int row = blockIdx.x * 4 + (threadIdx.x >> 6);
    int ln = threadIdx.x & 63;
    const float* src = t + (size_t)row * 512 + ln * 8;
    float4 a = *(const float4*)src;
    float4 b = *(const float4*)(src + 4);
    float ss = a.x * a.x + a.y * a.y + a.z * a.z + a.w * a.w
             + b.x * b.x + b.y * b.y + b.z * b.z + b.w * b.w;
#pragma unroll
    for (int m = 32; m >= 1; m >>= 1) ss += __shfl_xor(ss, m);
    float r = rsqrtf(ss * (1.0f / 512.0f) + EPSF);
    const float* wp = w + ln * 8;
    float4 w0 = *(const float4*)wp;
    float4 w1 = *(const float4*)(wp + 4);
    f16x8 o;
    o[0] = (_Float16)(a.x * r * w0.x);
    o[1] = (_Float16)(a.y * r * w0.y);
    o[2] = (_Float16)(a.z * r * w0.z);
    o[3] = (_Float16)(a.w * r * w0.w);
    o[4] = (_Float16)(b.x * r * w1.x);
    o[5] = (_Float16)(b.y * r * w1.y);
    o[6] = (_Float16)(b.z * r * w1.z);
    o[7] = (_Float16)(b.w * r * w1.w);
    *(f16x8*)(xn + (size_t)row * 512 + ln * 8) = o;
    return;
  }
  // coalesced weight transpose+cast via LDS, 64x64 tiles
  int b = blockIdx.x - 2048;
  const float* src; half_t* dst; int N, tk, tn;
  if (b < 192) { src = wqkv; dst = wqt; N = 1536; tk = b / 24; tn = b - tk * 24; }
  else { b -= 192; src = wout; dst = wot; N = 512; tk = b >> 3; tn = b & 7; }
  int c = threadIdx.x & 63;
  int r0 = threadIdx.x >> 6;
#pragma unroll
  for (int i = 0; i < 16; ++i) {
    int r = i * 4 + r0;
    tile[r][c] = (_Float16)src[(size_t)(tk * 64 + r) * N + tn * 64 + c];
  }
  __syncthreads();
#pragma unroll
  for (int i = 0; i < 16; ++i) {
    int n = i * 4 + r0;
    dst[(size_t)(tn * 64 + n) * 512 + tk * 64 + c] = tile[c][n];
  }
}

// ---------------- shared GEMM core: C[128][128] tile = A[M][K] @ Bt[N][K]^T ----------------
__device__ __forceinline__ void gemm_core(const half_t* __restrict__ A,
                                          const half_t* __restrict__ Bt,
                                          int m0, int n0, int Ksz,
                                          half_t* Al, half_t* Bl,
                                          f32x4 acc[4][4]) {
  int wv = threadIdx.x >> 6, ln = threadIdx.x & 63;
  int wm = (wv >> 1) << 6, wn = (wv & 1) << 6;
  for (int kt = 0; kt < Ksz; kt += 64) {
#pragma unroll
    for (int i = 0; i < 4; ++i) {
      int seg = wv * 4 + i;          // 16 segs x 8 rows = 128 rows
      int r = seg * 8 + (ln >> 3);
      int cb = ((ln & 7) * 16) ^ ((r & 7) << 4);   // pre-swizzled source col
      gload16((const char*)(A + (size_t)(m0 + r) * Ksz + kt) + cb, (char*)Al + seg * 1024);
      gload16((const char*)(Bt + (size_t)(n0 + r) * Ksz + kt) + cb, (char*)Bl + seg * 1024);
    }
    __syncthreads();
#pragma unroll
    for (int kc = 0; kc < 2; ++kc) {
      f16x8 af[4], bf[4];
#pragma unroll
      for (int mt = 0; mt < 4; ++mt) {
        int rr = wm + mt * 16 + (ln & 15);
        af[mt] = *(const f16x8*)((const char*)Al + rr * 128 +
                                 ((kc * 64 + (ln >> 4) * 16) ^ ((rr & 7) << 4)));
      }
#pragma unroll
      for (int nt = 0; nt < 4; ++nt) {
        int rr = wn + nt * 16 + (ln & 15);
        bf[nt] = *(const f16x8*)((const char*)Bl + rr * 128 +
                                 ((kc * 64 + (ln >> 4) * 16) ^ ((rr & 7) << 4)));
      }
#pragma unroll
      for (int mt = 0; mt < 4; ++mt)
#pragma unroll
        for (int nt = 0; nt < 4; ++nt)
          acc[mt][nt] = __builtin_amdgcn_mfma_f32_16x16x32_f16(af[mt], bf[nt], acc[mt][nt], 0, 0, 0);
    }
    __syncthreads();
  }
}

// ---------------- QKV GEMM: scatter q (log2e-scaled) / k / vT (k-slot-permuted) ----------------
__global__ __launch_bounds__(256, 2) void k_gemm_qkv(const half_t* __restrict__ A,
                                                     const half_t* __restrict__ Bt,
                                                     half_t* __restrict__ q,
                                                     half_t* __restrict__ kk,
                                                     half_t* __restrict__ vt) {
  __shared__ __align__(16) half_t Al[128 * 64];
  __shared__ __align__(16) half_t Bl[128 * 64];
  f32x4 acc[4][4];
  f32x4 z = {0.f, 0.f, 0.f, 0.f};
#pragma unroll
  for (int i = 0; i < 4; ++i)
#pragma unroll
    for (int j = 0; j < 4; ++j) acc[i][j] = z;
  int m0 = blockIdx.x * 128, n0 = blockIdx.y * 128;
  gemm_core(A, Bt, m0, n0, 512, Al, Bl, acc);
  int wv = threadIdx.x >> 6, ln = threadIdx.x & 63;
  int wm = (wv >> 1) << 6, wn = (wv & 1) << 6;
#pragma unroll
  for (int mt = 0; mt < 4; ++mt) {
#pragma unroll
    for (int nt = 0; nt < 4; ++nt) {
      int gn = n0 + wn + nt * 16 + (ln & 15);
      int qkv_i = gn >> 9;         // 0,1,2
      int h = (gn >> 6) & 7;
      int d = gn & 63;
#pragma unroll
      for (int j = 0; j < 4; ++j) {
        int gm = m0 + wm + mt * 16 + (ln >> 4) * 4 + j;   // token id
        int head = ((gm >> 12) << 3) | h;                 // b*8+h
        int n = gm & 4095;
        float av = acc[mt][nt][j];
        if (qkv_i == 0)      q [((size_t)head * 4096 + n) * 64 + d] = (_Float16)(av * LOG2E);
        else if (qkv_i == 1) kk[((size_t)head * 4096 + n) * 64 + d] = (_Float16)av;
        else {
          // V^T with kv-col permutation within each aligned 32-chunk:
          // kv = h16*16 + g*4 + j2  ->  pos = g*8 + h16*4 + j2
          int pcol = (n & ~31) | (((n >> 2) & 3) << 3) | (((n >> 4) & 1) << 2) | (n & 3);
          vt[((size_t)head * 64 + d) * 4096 + pcol] = (_Float16)av;
        }
      }
    }
  }
}

// ---------------- out GEMM: [8192,512]@[512,512] -> fp32 d_out ----------------
__global__ __launch_bounds__(256, 2) void k_gemm_out(const half_t* __restrict__ A,
                                                     const half_t* __restrict__ Bt,
                                                     float* __restrict__ out) {
  __shared__ __align__(16) half_t Al[128 * 64];
  __shared__ __align__(16) half_t Bl[128 * 64];
  f32x4 acc[4][4];
  f32x4 z = {0.f, 0.f, 0.f, 0.f};
#pragma unroll
  for (int i = 0; i < 4; ++i)
#pragma unroll
    for (int j = 0; j < 4; ++j) acc[i][j] = z;
  int m0 = blockIdx.x * 128, n0 = blockIdx.y * 128;
  gemm_core(A, Bt, m0, n0, 512, Al, Bl, acc);
  int wv = threadIdx.x >> 6, ln = threadIdx.x & 63;
  int wm = (wv >> 1) << 6, wn = (wv & 1) << 6;
#pragma unroll
  for (int mt = 0; mt < 4; ++mt)
#pragma unroll
    for (int nt = 0; nt < 4; ++nt) {
      int gn = n0 + wn + nt * 16 + (ln & 15);
#pragma unroll
      for (int j = 0; j < 4; ++j) {
        int gm = m0 + wm + mt * 16 + (ln >> 4) * 4 + j;
        out[(size_t)gm * 512 + gn] = acc[mt][nt][j];
      }
    }
}

// ---------------- flash attention: 8 waves x 16 q rows, QBLK=128 (R13, best verified) ----------------
// S^T = mfma(K, Q) with C pre-initialized to -mrun; relative defer-max with the
// cross-lane max moved into the rare rescale branch (common path is shfl-free);
// O^T = mfma(V^T, P^T); l = mfma(ones, P^T).
__global__ __launch_bounds__(512, 4) void k_attn(const half_t* __restrict__ q,
                                                 const half_t* __restrict__ kg,
                                                 const half_t* __restrict__ vt,
                                                 half_t* __restrict__ ao) {
  __shared__ __align__(16) char lds[32768];   // [2 bufs][K 8KB | V^T 8KB]
  const int wv = threadIdx.x >> 6, ln = threadIdx.x & 63;
  const int bid = blockIdx.x;
  const int lin = (bid & 7) * 64 + (bid >> 3);   // XCD-chunk swizzle (512 = 8*64)
  const int head = lin >> 5;
  const int qt = lin & 31;
  const int q0 = qt * 128 + wv * 16;
  const char* qh = (const char*)(q  + (size_t)head * 4096 * 64);
  const char* kh = (const char*)(kg + (size_t)head * 4096 * 64);
  const char* vh = (const char*)(vt + (size_t)head * 64 * 4096);

  // Q fragments (B-operand: col = q-row = ln&15, k-slots = d)
  f16x8 qf[2];
#pragma unroll
  for (int kc = 0; kc < 2; ++kc) {
    int r = q0 + (ln & 15);
    qf[kc] = *(const f16x8*)(qh + (size_t)r * 128 + kc * 64 + (ln >> 4) * 16);
  }

  // staging: one K seg + one V seg per wave (8 waves cover 8KB each)
  const int sr = wv * 8 + (ln >> 3);
  const int cb = ((ln & 7) * 16) ^ ((sr & 7) << 4);
  const char* ks = kh + (size_t)sr * 128 + cb;
  const char* vs = vh + (size_t)sr * 8192 + cb;
  const int lo = wv * 1024;

  float mrun = 0.0f;       // relative defer-max: m >= truemax-11 holds from tile 0
  f32x4 oacc[4];
  f32x4 lacc;
  const f32x4 z = {0.f, 0.f, 0.f, 0.f};
  lacc = z;
#pragma unroll
  for (int dt = 0; dt < 4; ++dt) oacc[dt] = z;
  f16x8 ones;
#pragma unroll
  for (int e = 0; e < 8; ++e) ones[e] = (_Float16)1.0f;

  // prologue: stage tile 0 into buf 0
  gload16(ks, lds + lo);
  gload16(vs, lds + 8192 + lo);
  ks += 8192; vs += 128;
  __syncthreads();

  int cur = 0;
#pragma unroll 1
  for (int t = 0; t < 64; ++t) {
    if (t < 63) {   // issue next-tile prefetch first; lands during compute
      char* base = lds + (cur ^ 1) * 16384;
      gload16(ks, base + lo);
      gload16(vs, base + 8192 + lo);
      ks += 8192; vs += 128;
    }
    const char* Kb = lds + cur * 16384;
    const char* Vb = Kb + 8192;

    // S^T = K * Q^T - m : C[row=kv][col=q], C-init = -mrun (per-lane q max)
    f32x4 s[4];
    {
      float nm = -mrun;
      f32x4 mi = {nm, nm, nm, nm};
      s[0] = mi; s[1] = mi; s[2] = mi; s[3] = mi;
    }
    __builtin_amdgcn_s_setprio(1);
#pragma unroll
    for (int kc = 0; kc < 2; ++kc) {
      f16x8 kf[4];
#pragma unroll
      for (int kt = 0; kt < 4; ++kt) {
        int rr = kt * 16 + (ln & 15);
        kf[kt] = *(const f16x8*)(Kb + rr * 128 + ((kc * 64 + (ln >> 4) * 16) ^ ((rr & 7) << 4)));
      }
#pragma unroll
      for (int kt = 0; kt < 4; ++kt)
        s[kt] = __builtin_amdgcn_mfma_f32_16x16x32_f16(kf[kt], qf[kc], s[kt], 0, 0, 0);
    }
    __builtin_amdgcn_s_setprio(0);

    // V fragments: single b128 per (kc,dt) thanks to k-slot-permuted global layout
    f16x8 vf[2][4];
#pragma unroll
    for (int dt = 0; dt < 4; ++dt) {
      int rr = dt * 16 + (ln & 15);
      int sw = (rr & 7) << 4;
      vf[0][dt] = *(const f16x8*)(Vb + rr * 128 + (((ln >> 4) * 16) ^ sw));
      vf[1][dt] = *(const f16x8*)(Vb + rr * 128 + ((64 + (ln >> 4) * 16) ^ sw));
    }

    // online softmax (log2 domain, already max-relative); one q per lane
    f16x8 pf[2];
    {
      // 16-value max in max3-friendly nested-triple shape (8 ops)
      float m0 = fmaxf(fmaxf(s[0][0], s[0][1]), s[0][2]);
      float m1 = fmaxf(fmaxf(s[0][3], s[1][0]), s[1][1]);
      float m2 = fmaxf(fmaxf(s[1][2], s[1][3]), s[2][0]);
      float m3 = fmaxf(fmaxf(s[2][1], s[2][2]), s[2][3]);
      float m4 = fmaxf(fmaxf(s[3][0], s[3][1]), s[3][2]);
      float m5 = fmaxf(fmaxf(m0, m1), m2);
      float m6 = fmaxf(fmaxf(m3, m4), s[3][3]);
      float tm = fmaxf(m5, m6);
      float p[4][4];
      // __any fires if ANY lane's LOCAL max breaches headroom; cross-lane max
      // (ds_bpermute-backed shfls) only needed to compute dlt in the rare path.
      if (__builtin_expect(__any(tm > 11.0f), 0)) {   // rare rescale path
        tm = fmaxf(tm, __shfl_xor(tm, 16));           // per-q max over 4 groups
        tm = fmaxf(tm, __shfl_xor(tm, 32));
        float dlt = fmaxf(tm, 0.0f);
        float sc = fast_exp2(-dlt);
        mrun += dlt;
        lacc[0] *= sc;
#pragma unroll
        for (int dt = 0; dt < 4; ++dt) {
          oacc[dt][0] *= sc; oacc[dt][1] *= sc;
          oacc[dt][2] *= sc; oacc[dt][3] *= sc;
        }
#pragma unroll
        for (int kt = 0; kt < 4; ++kt)
#pragma unroll
          for (int r = 0; r < 4; ++r) p[kt][r] = fast_exp2(s[kt][r] - dlt);
      } else {                                        // common path: shfl-free
#pragma unroll
        for (int kt = 0; kt < 4; ++kt)
#pragma unroll
          for (int r = 0; r < 4; ++r) p[kt][r] = fast_exp2(s[kt][r]);
      }
#pragma unroll
      for (int kc = 0; kc < 2; ++kc) {
        union { f16x8 v; fp16v2 h[4]; } u;
        u.h[0] = __builtin_amdgcn_cvt_pkrtz(p[2 * kc][0], p[2 * kc][1]);
        u.h[1] = __builtin_amdgcn_cvt_pkrtz(p[2 * kc][2], p[2 * kc][3]);
        u.h[2] = __builtin_amdgcn_cvt_pkrtz(p[2 * kc + 1][0], p[2 * kc + 1][1]);
        u.h[3] = __builtin_amdgcn_cvt_pkrtz(p[2 * kc + 1][2], p[2 * kc + 1][3]);
        pf[kc] = u.v;
      }
    }

    // O^T += V^T * P^T ; l += ones * P^T (full kv sum lands in every lane)
    __builtin_amdgcn_s_setprio(1);
#pragma unroll
    for (int dt = 0; dt < 4; ++dt)
      oacc[dt] = __builtin_amdgcn_mfma_f32_16x16x32_f16(vf[0][dt], pf[0], oacc[dt], 0, 0, 0);
    lacc = __builtin_amdgcn_mfma_f32_16x16x32_f16(ones, pf[0], lacc, 0, 0, 0);
#pragma unroll
    for (int dt = 0; dt < 4; ++dt)
      oacc[dt] = __builtin_amdgcn_mfma_f32_16x16x32_f16(vf[1][dt], pf[1], oacc[dt], 0, 0, 0);
    lacc = __builtin_amdgcn_mfma_f32_16x16x32_f16(ones, pf[1], lacc, 0, 0, 0);
    __builtin_amdgcn_s_setprio(0);

    __syncthreads();   // drains vmcnt; prefetch had full compute phase to land
    cur ^= 1;
  }

  // epilogue: O^T / l -> attn_out [token][h*64+d] fp16
  const int b = head >> 3, h = head & 7;
  {
    float inv = 1.0f / lacc[0];
    int n = q0 + (ln & 15);
    half_t* dst = ao + ((size_t)(b * 4096 + n)) * 512 + h * 64 + (ln >> 4) * 4;
#pragma unroll
    for (int dt = 0; dt < 4; ++dt) {
      f16x4 o4;
      o4[0] = (_Float16)(oacc[dt][0] * inv);
      o4[1] = (_Float16)(oacc[dt][1] * inv);
      o4[2] = (_Float16)(oacc[dt][2] * inv);
      o4[3] = (_Float16)(oacc[dt][3] * inv);
      *(f16x4*)(dst + dt * 16) = o4;
    }
  }
}

extern "C" void kernel_launch(void* const* d_in, const int* in_sizes, int n_in,
                              void* d_out, int out_size, void* d_ws, size_t ws_size,
                              hipStream_t stream) {
  if (ws_size < WS_NEED_BYTES) return;  // loud failure if scratch too small
  const float* tokens = (const float*)d_in[0];
  const float* nw     = (const float*)d_in[1];
  const float* wqkv   = (const float*)d_in[2];
  const float* wout   = (const float*)d_in[3];
  float* out = (float*)d_out;
  half_t* ws = (half_t*)d_ws;
  half_t* xn  = ws + WS_XN;
  half_t* wqt = ws + WS_WQT;
  half_t* wot = ws + WS_WOT;
  half_t* qb  = ws + WS_Q;
  half_t* kb  = ws + WS_K;
  half_t* vtb = ws + WS_VT;
  half_t* aob = ws + WS_AO;

  k_prep<<<2304, 256, 0, stream>>>(tokens, nw, xn, wqkv, wout, wqt, wot);
  k_gemm_qkv<<<dim3(64, 12), 256, 0, stream>>>(xn, wqt, qb, kb, vtb);
  k_attn<<<512, 512, 0, stream>>>(qb, kb, vtb, aob);
  k_gemm_out<<<dim3(64, 4), 256, 0, stream>>>(aob, wot, out);
}